// Round 7
// baseline (684.775 us; speedup 1.0000x reference)
//
#include <hip/hip_runtime.h>
#include <hip/hip_bf16.h>
#include <math.h>

#define F_DIM 128
#define B_GRAPHS 64
#define AGG_WAVES 8

__device__ __forceinline__ float lrelu(float v, float s) {
    return v > 0.f ? v : s * v;
}

__device__ __forceinline__ int lower_bound_i(const int* __restrict__ a, int n, int v) {
    int lo = 0, hi = n;
    while (lo < hi) {
        int mid = (lo + hi) >> 1;
        if (a[mid] < v) lo = mid + 1; else hi = mid;
    }
    return lo;
}

// ---------------------------------------------------------------------------
// edge counts per dst, both channels (blockIdx.y = channel)
__global__ void count2_k(const int* __restrict__ ei0, const int* __restrict__ ei1,
                         int* __restrict__ c0, int* __restrict__ c1, int E) {
    const int* ei = blockIdx.y ? ei1 : ei0;
    int* cnt = blockIdx.y ? c1 : c0;
    int i = blockIdx.x * blockDim.x + threadIdx.x;
    if (i < E) atomicAdd(cnt + ei[E + i], 1);
}

// ---------------------------------------------------------------------------
// chunked exclusive scan over (cnt[i]+1), one block per channel
__global__ __launch_bounds__(1024) void scan2_k(const int* __restrict__ c0,
                                                const int* __restrict__ c1,
                                                int* __restrict__ s0, int* __restrict__ s1,
                                                int n, int tot) {
    const int* cnt = blockIdx.x ? c1 : c0;
    int* start = blockIdx.x ? s1 : s0;
    __shared__ int ssum[1024];
    int t = threadIdx.x;
    int chunk = (n + 1023) / 1024;
    int lo = t * chunk, hi = min(lo + chunk, n);
    int s = 0;
    for (int i = lo; i < hi; ++i) s += cnt[i] + 1;
    ssum[t] = s;
    __syncthreads();
    for (int offs = 1; offs < 1024; offs <<= 1) {
        int v = (t >= offs) ? ssum[t - offs] : 0;
        __syncthreads();
        ssum[t] += v;
        __syncthreads();
    }
    int excl = (t == 0) ? 0 : ssum[t - 1];
    for (int i = lo; i < hi; ++i) {
        start[i] = excl;
        excl += cnt[i] + 1;
    }
    if (t == 1023) start[n] = tot;
}

// ---------------------------------------------------------------------------
// dual GEMM fused with ONE channel's CSR scatter (atomics in prologue,
// deferred stores in epilogue; ~50us of scatter traffic hidden under ~55us
// of GEMM math).
__global__ __launch_bounds__(256) void gemm2_bias_scatter(
        const float* __restrict__ A,
        const float* __restrict__ Wl, const float* __restrict__ bl,
        const float* __restrict__ Wr, const float* __restrict__ br,
        float* __restrict__ Cl, float* __restrict__ Cr, int n,
        const int* __restrict__ ei, const int* __restrict__ st,
        int* __restrict__ cnt, int* __restrict__ ss,
        int E, int tot, int ipb) {
    // ---- scatter prologue ----
    int base = blockIdx.x * ipb;
    int lim = min(base + ipb, tot);
    int pos_0 = -1, pos_1 = -1;
    int src_0 = 0, src_1 = 0;
    #pragma unroll
    for (int q = 0; q < 2; ++q) {
        int it = base + q * 256 + (int)threadIdx.x;
        if (it < lim) {
            int pos, src;
            if (it < n) {                  // self loop -> slot 0
                pos = st[it];
                src = it;
            } else {
                int j = it - n;
                int dst = ei[E + j];
                src = ei[j];
                int o = atomicAdd(cnt + dst, -1);   // o in [deg..1]
                pos = st[dst] + o;
            }
            if (q == 0) { pos_0 = pos; src_0 = src; }
            else        { pos_1 = pos; src_1 = src; }
        }
    }
    // safety net if ipb ever exceeds 512
    for (int it = base + 512 + (int)threadIdx.x; it < lim; it += 256) {
        if (it < n) ss[st[it]] = it;
        else {
            int j = it - n;
            int dst = ei[E + j];
            int o = atomicAdd(cnt + dst, -1);
            ss[st[dst] + o] = ei[j];
        }
    }

    // ---- GEMM ----
    __shared__ float As[16][F_DIM];
    int row0 = blockIdx.x * 16;
    for (int i = threadIdx.x; i < 16 * F_DIM; i += 256) {
        int r = i >> 7, c = i & 127;
        int gr = row0 + r;
        As[r][c] = (gr < n) ? A[(size_t)gr * F_DIM + c] : 0.f;
    }
    __syncthreads();
    int c = threadIdx.x & 127;
    int rg = (threadIdx.x >> 7) * 8;
    float accl[8] = {0.f, 0.f, 0.f, 0.f, 0.f, 0.f, 0.f, 0.f};
    float accr[8] = {0.f, 0.f, 0.f, 0.f, 0.f, 0.f, 0.f, 0.f};
    for (int k = 0; k < F_DIM; k += 4) {
        float wl0 = Wl[(k + 0) * F_DIM + c];
        float wl1 = Wl[(k + 1) * F_DIM + c];
        float wl2 = Wl[(k + 2) * F_DIM + c];
        float wl3 = Wl[(k + 3) * F_DIM + c];
        float wr0 = Wr[(k + 0) * F_DIM + c];
        float wr1 = Wr[(k + 1) * F_DIM + c];
        float wr2 = Wr[(k + 2) * F_DIM + c];
        float wr3 = Wr[(k + 3) * F_DIM + c];
        #pragma unroll
        for (int j = 0; j < 8; ++j) {
            float4 a = *(const float4*)&As[rg + j][k];
            accl[j] += a.x * wl0 + a.y * wl1 + a.z * wl2 + a.w * wl3;
            accr[j] += a.x * wr0 + a.y * wr1 + a.z * wr2 + a.w * wr3;
        }
    }
    #pragma unroll
    for (int j = 0; j < 8; ++j) {
        int r = row0 + rg + j;
        if (r < n) {
            Cl[(size_t)r * F_DIM + c] = accl[j] + bl[c];
            Cr[(size_t)r * F_DIM + c] = accr[j] + br[c];
        }
    }

    // ---- scatter epilogue ----
    if (pos_0 >= 0) ss[pos_0] = src_0;
    if (pos_1 >= 0) ss[pos_1] = src_1;
}

// ---------------------------------------------------------------------------
// one wave per dst node; 16-lane group per edge (4 edges in flight, x2
// unroll = 8 gathers outstanding). Lane owns 8 channels (2x float4).
// Head h = sub-lanes 4h..4h+3, so e-reduce is 2 xor steps; cross-group
// combine (xor 16/32) once per node. No-max softmax (logits bounded ~1.5).
__global__ __launch_bounds__(512) void gat_agg(
        const float* __restrict__ xl, const float* __restrict__ xr,
        const float* __restrict__ att, const float* __restrict__ bias,
        const int* __restrict__ start, const int* __restrict__ sortedSrc,
        const int* __restrict__ batch, float* __restrict__ pool, int n) {
    __shared__ float accs[AGG_WAVES][F_DIM];
    __shared__ int gids[AGG_WAVES];
    int lane = threadIdx.x & 63;
    int wv = threadIdx.x >> 6;
    int grp = lane >> 4;       // which of 4 concurrent edges
    int sub = lane & 15;       // channel group: owns channels 8*sub..8*sub+7
    int node = blockIdx.x * AGG_WAVES + wv;

    if (node < n) {
        const float* xrp = xr + (size_t)node * F_DIM + sub * 8;
        float4 r0 = *(const float4*)(xrp + 0);
        float4 r1 = *(const float4*)(xrp + 4);
        float4 t0 = *(const float4*)(att + sub * 8 + 0);
        float4 t1 = *(const float4*)(att + sub * 8 + 4);

        int s = start[node];
        int e = start[node + 1];

        float d = 0.f;
        float4 a0 = {0.f, 0.f, 0.f, 0.f};
        float4 a1 = {0.f, 0.f, 0.f, 0.f};

        for (int i = s; i < e; i += 8) {
            int i0 = i + grp;
            int i1 = i + 4 + grp;
            bool v0 = i0 < e, v1 = i1 < e;
            int s0 = v0 ? sortedSrc[i0] : node;
            int s1 = v1 ? sortedSrc[i1] : node;
            const float* p0 = xl + (size_t)s0 * F_DIM + sub * 8;
            const float* p1 = xl + (size_t)s1 * F_DIM + sub * 8;
            float4 A0 = *(const float4*)(p0 + 0);
            float4 B0 = *(const float4*)(p0 + 4);
            float4 A1 = *(const float4*)(p1 + 0);
            float4 B1 = *(const float4*)(p1 + 4);

            float pa = lrelu(A0.x + r0.x, 0.2f) * t0.x + lrelu(A0.y + r0.y, 0.2f) * t0.y
                     + lrelu(A0.z + r0.z, 0.2f) * t0.z + lrelu(A0.w + r0.w, 0.2f) * t0.w
                     + lrelu(B0.x + r1.x, 0.2f) * t1.x + lrelu(B0.y + r1.y, 0.2f) * t1.y
                     + lrelu(B0.z + r1.z, 0.2f) * t1.z + lrelu(B0.w + r1.w, 0.2f) * t1.w;
            float pb = lrelu(A1.x + r0.x, 0.2f) * t0.x + lrelu(A1.y + r0.y, 0.2f) * t0.y
                     + lrelu(A1.z + r0.z, 0.2f) * t0.z + lrelu(A1.w + r0.w, 0.2f) * t0.w
                     + lrelu(B1.x + r1.x, 0.2f) * t1.x + lrelu(B1.y + r1.y, 0.2f) * t1.y
                     + lrelu(B1.z + r1.z, 0.2f) * t1.z + lrelu(B1.w + r1.w, 0.2f) * t1.w;
            // reduce over the 4 sub-lanes of each head (bits 0-1 of sub)
            pa += __shfl_xor(pa, 1);  pa += __shfl_xor(pa, 2);
            pb += __shfl_xor(pb, 1);  pb += __shfl_xor(pb, 2);

            float wa = v0 ? __expf(pa) : 0.f;
            float wb = v1 ? __expf(pb) : 0.f;
            d += wa + wb;
            a0.x += wa * A0.x + wb * A1.x;  a0.y += wa * A0.y + wb * A1.y;
            a0.z += wa * A0.z + wb * A1.z;  a0.w += wa * A0.w + wb * A1.w;
            a1.x += wa * B0.x + wb * B1.x;  a1.y += wa * B0.y + wb * B1.y;
            a1.z += wa * B0.z + wb * B1.z;  a1.w += wa * B0.w + wb * B1.w;
        }

        // combine the 4 edge-groups (xor 16/32 preserves sub -> same channels)
        #pragma unroll
        for (int sh = 16; sh <= 32; sh <<= 1) {
            d    += __shfl_xor(d, sh);
            a0.x += __shfl_xor(a0.x, sh);  a0.y += __shfl_xor(a0.y, sh);
            a0.z += __shfl_xor(a0.z, sh);  a0.w += __shfl_xor(a0.w, sh);
            a1.x += __shfl_xor(a1.x, sh);  a1.y += __shfl_xor(a1.y, sh);
            a1.z += __shfl_xor(a1.z, sh);  a1.w += __shfl_xor(a1.w, sh);
        }

        if (grp == 0) {
            float inv = 1.f / d;   // d > 0 (self loop always present)
            float4 bi0 = *(const float4*)(bias + sub * 8 + 0);
            float4 bi1 = *(const float4*)(bias + sub * 8 + 4);
            float* dst = &accs[wv][sub * 8];
            dst[0] = lrelu(a0.x * inv + bi0.x, 0.01f);
            dst[1] = lrelu(a0.y * inv + bi0.y, 0.01f);
            dst[2] = lrelu(a0.z * inv + bi0.z, 0.01f);
            dst[3] = lrelu(a0.w * inv + bi0.w, 0.01f);
            dst[4] = lrelu(a1.x * inv + bi1.x, 0.01f);
            dst[5] = lrelu(a1.y * inv + bi1.y, 0.01f);
            dst[6] = lrelu(a1.z * inv + bi1.z, 0.01f);
            dst[7] = lrelu(a1.w * inv + bi1.w, 0.01f);
        }
        if (lane == 0) gids[wv] = batch[node];
    } else {
        if (lane == 0) gids[wv] = -1;
        if (grp == 0) {
            float* dst = &accs[wv][sub * 8];
            #pragma unroll
            for (int j = 0; j < 8; ++j) dst[j] = 0.f;
        }
    }
    __syncthreads();

    if (threadIdx.x < F_DIM) {
        int t = threadIdx.x;
        float sum = 0.f;
        int cg = -1;
        #pragma unroll
        for (int r = 0; r < AGG_WAVES; ++r) {
            int g = gids[r];
            if (g < 0) continue;
            if (g != cg) {
                if (cg >= 0) atomicAdd(pool + (size_t)cg * F_DIM + t, sum);
                sum = 0.f;
                cg = g;
            }
            sum += accs[r][t];
        }
        if (cg >= 0) atomicAdd(pool + (size_t)cg * F_DIM + t, sum);
    }
}

// ---------------------------------------------------------------------------
// branch fc, both channels (128 blocks): node count per graph via binary
// search on the SORTED batch array (atomic-free), then 128x128 mat-vec.
__global__ void branch_fc2(const float* __restrict__ pool0, const float* __restrict__ pool1,
                           const int* __restrict__ batch0, const int* __restrict__ batch1,
                           const float* __restrict__ W0, const float* __restrict__ b0,
                           const float* __restrict__ W1, const float* __restrict__ b1,
                           float* __restrict__ out0, float* __restrict__ out1, int n) {
    int ch = blockIdx.x >> 6;
    int g  = blockIdx.x & 63;
    const float* pool  = ch ? pool1 : pool0;
    const int*   batch = ch ? batch1 : batch0;
    const float* W     = ch ? W1 : W0;
    const float* b     = ch ? b1 : b0;
    float*       out   = ch ? out1 : out0;

    int lo = lower_bound_i(batch, n, g);
    int hi = lower_bound_i(batch, n, g + 1);
    float c = fmaxf((float)(hi - lo), 1.f);

    __shared__ float xm[F_DIM];
    int j = threadIdx.x;  // 128 threads
    xm[j] = pool[(size_t)g * F_DIM + j] / c;
    __syncthreads();
    float acc = b[j];
    for (int k = 0; k < F_DIM; ++k) acc += xm[k] * W[k * F_DIM + j];
    out[(size_t)g * F_DIM + j] = lrelu(acc, 0.01f);
}

// ---------------------------------------------------------------------------
// head: xc = concat(x1,x2); fc1+lrelu; fc2+lrelu; out
__global__ void head_k(const float* __restrict__ x1, const float* __restrict__ x2,
                       const float* __restrict__ W1, const float* __restrict__ b1,
                       const float* __restrict__ W2, const float* __restrict__ b2,
                       const float* __restrict__ Wo, const float* __restrict__ bo,
                       float* __restrict__ out) {
    int g = blockIdx.x;
    int t = threadIdx.x;  // 256 threads
    __shared__ float xc[2 * F_DIM];
    __shared__ float h1[F_DIM];
    __shared__ float h2[16];
    xc[t] = (t < F_DIM) ? x1[(size_t)g * F_DIM + t] : x2[(size_t)g * F_DIM + (t - F_DIM)];
    __syncthreads();
    if (t < F_DIM) {
        float acc = b1[t];
        for (int k = 0; k < 2 * F_DIM; ++k) acc += xc[k] * W1[k * F_DIM + t];
        h1[t] = lrelu(acc, 0.01f);
    }
    __syncthreads();
    if (t < 16) {
        float acc = b2[t];
        for (int k = 0; k < F_DIM; ++k) acc += h1[k] * W2[k * 16 + t];
        h2[t] = lrelu(acc, 0.01f);
    }
    __syncthreads();
    if (t == 0) {
        float acc = bo[0];
        for (int k = 0; k < 16; ++k) acc += h2[k] * Wo[k];
        out[g] = acc;
    }
}

// ---------------------------------------------------------------------------
extern "C" void kernel_launch(void* const* d_in, const int* in_sizes, int n_in,
                              void* d_out, int out_size, void* d_ws, size_t ws_size,
                              hipStream_t stream) {
    const int N = in_sizes[0] / F_DIM;   // 50000
    const int E = in_sizes[1] / 2;       // 800000
    const int TOT = E + N;

    const int* ei0    = (const int*)d_in[1];
    const int* ei1    = (const int*)d_in[4];
    const int* batch0 = (const int*)d_in[2];
    const int* batch1 = (const int*)d_in[5];

    // workspace layout
    float* w = (float*)d_ws;
    size_t off = 0;
    float* xl   = w + off; off += (size_t)N * F_DIM;      // shared between channels
    float* xr   = w + off; off += (size_t)N * F_DIM;
    float* xfc0 = w + off; off += (size_t)B_GRAPHS * F_DIM;
    float* xfc1 = w + off; off += (size_t)B_GRAPHS * F_DIM;
    int* ss0    = (int*)(w + off); off += (size_t)TOT;
    int* ss1    = (int*)(w + off); off += (size_t)TOT;
    int* st0    = (int*)(w + off); off += (size_t)(N + 1);
    int* st1    = (int*)(w + off); off += (size_t)(N + 1);
    // contiguous zero-region: pool0 | pool1 | cnt0 | cnt1
    float* pool0 = w + off;
    float* pool1 = pool0 + (size_t)B_GRAPHS * F_DIM;
    int*   cnt0  = (int*)(pool1 + (size_t)B_GRAPHS * F_DIM);
    int*   cnt1  = cnt0 + N;
    const size_t zeroBytes = (2 * (size_t)B_GRAPHS * F_DIM + 2 * (size_t)N) * 4;

    const int edgeBlocks = (E + 255) / 256;
    const int gemmBlocks = (N + 15) / 16;   // 3125
    const int aggBlocks  = (N + AGG_WAVES - 1) / AGG_WAVES;
    const int ipb = (TOT + gemmBlocks - 1) / gemmBlocks;   // 272

    hipMemsetAsync(pool0, 0, zeroBytes, stream);
    hipLaunchKernelGGL(count2_k, dim3(edgeBlocks, 2), dim3(256), 0, stream,
                       ei0, ei1, cnt0, cnt1, E);
    hipLaunchKernelGGL(scan2_k, dim3(2), dim3(1024), 0, stream,
                       cnt0, cnt1, st0, st1, N, TOT);

    // channel 0: GEMM + its scatter, then aggregation
    hipLaunchKernelGGL(gemm2_bias_scatter, dim3(gemmBlocks), dim3(256), 0, stream,
                       (const float*)d_in[0],
                       (const float*)d_in[6], (const float*)d_in[7],
                       (const float*)d_in[8], (const float*)d_in[9],
                       xl, xr, N, ei0, st0, cnt0, ss0, E, TOT, ipb);
    hipLaunchKernelGGL(gat_agg, dim3(aggBlocks), dim3(512), 0, stream,
                       xl, xr, (const float*)d_in[10], (const float*)d_in[11],
                       st0, ss0, batch0, pool0, N);

    // channel 1
    hipLaunchKernelGGL(gemm2_bias_scatter, dim3(gemmBlocks), dim3(256), 0, stream,
                       (const float*)d_in[3],
                       (const float*)d_in[14], (const float*)d_in[15],
                       (const float*)d_in[16], (const float*)d_in[17],
                       xl, xr, N, ei1, st1, cnt1, ss1, E, TOT, ipb);
    hipLaunchKernelGGL(gat_agg, dim3(aggBlocks), dim3(512), 0, stream,
                       xl, xr, (const float*)d_in[18], (const float*)d_in[19],
                       st1, ss1, batch1, pool1, N);

    hipLaunchKernelGGL(branch_fc2, dim3(2 * B_GRAPHS), dim3(F_DIM), 0, stream,
                       pool0, pool1, batch0, batch1,
                       (const float*)d_in[12], (const float*)d_in[13],
                       (const float*)d_in[20], (const float*)d_in[21],
                       xfc0, xfc1, N);

    hipLaunchKernelGGL(head_k, dim3(B_GRAPHS), dim3(256), 0, stream,
                       xfc0, xfc1,
                       (const float*)d_in[22], (const float*)d_in[23],
                       (const float*)d_in[24], (const float*)d_in[25],
                       (const float*)d_in[26], (const float*)d_in[27],
                       (float*)d_out);
}